// Round 1
// baseline (78.547 us; speedup 1.0000x reference)
//
#include <hip/hip_runtime.h>

#define NINST 64
#define ACC_STRIDE 512   // floats per image in accumulator region
// per-image acc layout:
//  [0,64)    counts
//  [64,256)  sum3  (k*3+c)
//  [256,320) h255 segment sums
//  [320]     h0 (label-0 huber-to-0 sum)
#define OFF_CNT  0
#define OFF_SUM  64
#define OFF_H255 256
#define OFF_H0   320
#define LAMBDA_SEP 300.0f

#define P1_GX 128        // pass1 grid.x (512 blocks total = 2/CU)
#define P1_THREADS 512
#define P1_WAVES (P1_THREADS / 64)
#define P2_GX 128        // pass2 grid.x (1024-thread blocks)
#define P3_GX 32         // pass3 grid.x
#define P3_TILE 256      // bg pixels staged per pass3 tile
#define CNT_STRIDE 64    // uints between per-image bg counters (256B)
#define BGBUF 512        // per-block LDS bg staging capacity (mean ~60/block)

__device__ __forceinline__ float huber1(float x, float c) {
    float d = fabsf(x - c);
    return d < 1.0f ? 0.5f * d * d : d - 0.5f;
}

// Pass 1 (grouped broadcast): segment sums with 8 pixels retired per LDS read.
// Wave = 8 groups x 8 lanes; group g reads staged slot j*8+g (8 distinct 16B
// slots span all 32 banks -> conflict-free); the 8 lanes of a group cover the
// 64 bins (lane sub-index s owns bins 8s..8s+7 in 32 VGPR accumulators).
// grid = (P1_GX, B), 512 threads.
__global__ __launch_bounds__(P1_THREADS, 4)
void k_pass1(const float* __restrict__ pred, const float* __restrict__ targ,
             float* __restrict__ acc, unsigned* __restrict__ bgcnt,
             float* __restrict__ bglist, int maxbg, int N) {
    __shared__ float4 s_stage[P1_WAVES][256];   // wave-private pixel staging (reused for reduce)
    __shared__ float4 s_red[P1_WAVES][NINST];   // per-wave per-bin (cnt,sx,sy,sz)
    __shared__ float s_corr255[NINST];
    __shared__ float s_corr0;
    __shared__ float s_bgbuf[BGBUF * 3];
    __shared__ unsigned s_bgn;
    __shared__ unsigned s_base;
    int tid = threadIdx.x;
    int lane = tid & 63;
    int wv = tid >> 6;
    int grp = lane >> 3;           // which staged pixel column this lane reads
    int s8 = (lane & 7) << 3;      // lane's bin base (bins s8..s8+7)
    if (tid < NINST) s_corr255[tid] = 0.0f;
    if (tid == 0) { s_corr0 = 0.0f; s_bgn = 0u; }
    __syncthreads();

    int b = blockIdx.y;
    const float* bp = pred + (size_t)b * 3 * N;
    const float* bt = targ + (size_t)b * 3 * N;
    const float4* t0 = (const float4*)bt;
    const float4* p0 = (const float4*)bp;
    const float4* p1 = (const float4*)(bp + N);
    const float4* p2 = (const float4*)(bp + 2 * N);
    unsigned* bgc = &bgcnt[(size_t)b * CNT_STRIDE];
    float* bgl = bglist + (size_t)b * maxbg * 3;
    float* g = acc + (size_t)b * ACC_STRIDE;

    float cnt[8], sx[8], sy[8], sz[8];   // lane's 8 bins: s8..s8+7
#pragma unroll
    for (int t = 0; t < 8; t++) { cnt[t] = 0.0f; sx[t] = 0.0f; sy[t] = 0.0f; sz[t] = 0.0f; }

    int M = N >> 2;
    int stride = gridDim.x * blockDim.x;
    // wave-uniform loop bound: base is the wave's first quad index
    for (int base = blockIdx.x * blockDim.x + wv * 64; base < M; base += stride) {
        int i = base + lane;
        float xx[4], yy[4], zz[4];
        int labs[4];
        if (i < M) {
            float4 t = t0[i], a = p0[i], c = p1[i], d = p2[i];
            float tt[4] = {t.x, t.y, t.z, t.w};
            xx[0] = a.x; xx[1] = a.y; xx[2] = a.z; xx[3] = a.w;
            yy[0] = c.x; yy[1] = c.y; yy[2] = c.z; yy[3] = c.w;
            zz[0] = d.x; zz[1] = d.y; zz[2] = d.z; zz[3] = d.w;
#pragma unroll
            for (int j = 0; j < 4; j++) {
                int lab = (int)(tt[j] * 0.25f + 0.5f);   // exact: labels are multiples of 4
                labs[j] = lab;
                // rare huber corrections (channel within 1 of the constant)
                float dx = 255.0f - xx[j], dy = 255.0f - yy[j], dz = 255.0f - zz[j];
                float corr = 0.0f;
                if (dx < 1.0f) { float e = 1.0f - dx; corr += 0.5f * e * e; }
                if (dy < 1.0f) { float e = 1.0f - dy; corr += 0.5f * e * e; }
                if (dz < 1.0f) { float e = 1.0f - dz; corr += 0.5f * e * e; }
                if (corr != 0.0f) atomicAdd(&s_corr255[lab], corr);
                if (lab == 0) {
                    float c0 = 0.0f;
                    if (xx[j] < 1.0f) { float e = 1.0f - xx[j]; c0 += 0.5f * e * e; }
                    if (yy[j] < 1.0f) { float e = 1.0f - yy[j]; c0 += 0.5f * e * e; }
                    if (zz[j] < 1.0f) { float e = 1.0f - zz[j]; c0 += 0.5f * e * e; }
                    if (c0 != 0.0f) atomicAdd(&s_corr0, c0);
                    unsigned idx = atomicAdd(&s_bgn, 1u);       // rare (~1.6% of px)
                    if (idx < BGBUF) {
                        s_bgbuf[idx * 3 + 0] = xx[j];
                        s_bgbuf[idx * 3 + 1] = yy[j];
                        s_bgbuf[idx * 3 + 2] = zz[j];
                    } else {
                        unsigned gi = atomicAdd(bgc, 1u);
                        if ((int)gi < maxbg) {
                            bgl[(size_t)gi * 3 + 0] = xx[j];
                            bgl[(size_t)gi * 3 + 1] = yy[j];
                            bgl[(size_t)gi * 3 + 2] = zz[j];
                        }
                    }
                }
            }
        } else {
#pragma unroll
            for (int j = 0; j < 4; j++) { xx[j] = yy[j] = zz[j] = 0.0f; labs[j] = -1; }
        }
        // stage 4 pixels: slot j*64+lane -> contiguous 16B per lane (conflict-free)
#pragma unroll
        for (int j = 0; j < 4; j++)
            s_stage[wv][j * 64 + lane] =
                make_float4(xx[j], yy[j], zz[j], __int_as_float(labs[j]));
        // grouped broadcast accumulate: one ds_read_b128 retires 8 pixels.
        // (same-wave write->read ordering via compiler lgkmcnt, as before)
#pragma unroll 4
        for (int j = 0; j < 32; j++) {
            float4 v = s_stage[wv][(j << 3) + grp];
            int rel = __float_as_int(v.w) - s8;      // in [0,8) iff pixel is in lane's bins
#pragma unroll
            for (int t = 0; t < 8; t++) {
                float m = (rel == t) ? 1.0f : 0.0f;
                cnt[t] += m;
                sx[t] = fmaf(m, v.x, sx[t]);
                sy[t] = fmaf(m, v.y, sy[t]);
                sz[t] = fmaf(m, v.z, sz[t]);
            }
        }
    }

    // ---- per-wave reduction over the 8 groups, via two transpose rounds ----
    // Round A: bins with (b&7) < 4. Writer lane L=(8g+s) puts bin (8s+q) at
    // slot 32g+4s+q; reducer lane l<32 (l=4s+q) sums slots g*32+l over g.
#pragma unroll
    for (int q = 0; q < 4; q++)
        s_stage[wv][(lane << 2) + q] = make_float4(cnt[q], sx[q], sy[q], sz[q]);
    __syncthreads();
    {
        int l = lane & 31;
        float4 ra = make_float4(0.0f, 0.0f, 0.0f, 0.0f);
#pragma unroll
        for (int gg = 0; gg < 8; gg++) {
            float4 p = s_stage[wv][gg * 32 + l];
            ra.x += p.x; ra.y += p.y; ra.z += p.z; ra.w += p.w;
        }
        if (lane < 32) s_red[wv][((l >> 2) << 3) + (l & 3)] = ra;
    }
    __syncthreads();
    // Round B: bins with (b&7) >= 4
#pragma unroll
    for (int q = 0; q < 4; q++)
        s_stage[wv][(lane << 2) + q] = make_float4(cnt[q + 4], sx[q + 4], sy[q + 4], sz[q + 4]);
    __syncthreads();
    {
        int l = lane & 31;
        float4 rb = make_float4(0.0f, 0.0f, 0.0f, 0.0f);
#pragma unroll
        for (int gg = 0; gg < 8; gg++) {
            float4 p = s_stage[wv][gg * 32 + l];
            rb.x += p.x; rb.y += p.y; rb.z += p.z; rb.w += p.w;
        }
        if (lane >= 32) s_red[wv][((l >> 2) << 3) + 4 + (l & 3)] = rb;
    }
    __syncthreads();

    // flush bg staging buffer: one global atomic per block, coalesced copy
    unsigned nloc = s_bgn < (unsigned)BGBUF ? s_bgn : (unsigned)BGBUF;
    if (tid == 0) s_base = atomicAdd(bgc, nloc);
    __syncthreads();
    {
        unsigned base3 = s_base * 3u;
        unsigned lim3 = (unsigned)maxbg * 3u;
        for (unsigned i = tid; i < nloc * 3u; i += blockDim.x) {
            if (base3 + i < lim3) bgl[base3 + i] = s_bgbuf[i];
        }
    }

    // cross-wave reduce + block-level global atomics; derive h255/h0 algebraically
    if (tid < NINST) {
        float c = 0.0f, x = 0.0f, y = 0.0f, z = 0.0f;
#pragma unroll
        for (int w = 0; w < P1_WAVES; w++) {
            float4 r = s_red[w][tid];
            c += r.x; x += r.y; y += r.z; z += r.w;
        }
        float s3 = x + y + z;
        atomicAdd(&g[OFF_CNT + tid], c);
        atomicAdd(&g[OFF_SUM + tid * 3 + 0], x);
        atomicAdd(&g[OFF_SUM + tid * 3 + 1], y);
        atomicAdd(&g[OFF_SUM + tid * 3 + 2], z);
        atomicAdd(&g[OFF_H255 + tid], 763.5f * c - s3 + s_corr255[tid]);
        if (tid == 0) atomicAdd(&g[OFF_H0], s3 - 1.5f * c + s_corr0);
    }

    // tail pixels (N % 4): direct global accumulation, exact huber
    if (blockIdx.x == 0 && tid < (N & 3)) {
        int i = (M << 2) + tid;
        float t = bt[i], x = bp[i], y = bp[N + i], z = bp[2 * N + i];
        int lab = (int)(t * 0.25f + 0.5f);
        atomicAdd(&g[OFF_CNT + lab], 1.0f);
        atomicAdd(&g[OFF_SUM + lab * 3 + 0], x);
        atomicAdd(&g[OFF_SUM + lab * 3 + 1], y);
        atomicAdd(&g[OFF_SUM + lab * 3 + 2], z);
        atomicAdd(&g[OFF_H255 + lab], huber1(x, 255.f) + huber1(y, 255.f) + huber1(z, 255.f));
        if (lab == 0) {
            atomicAdd(&g[OFF_H0], huber1(x, 0.f) + huber1(y, 0.f) + huber1(z, 0.f));
            unsigned gi = atomicAdd(bgc, 1u);
            if ((int)gi < maxbg) {
                bgl[(size_t)gi * 3 + 0] = x;
                bgl[(size_t)gi * 3 + 1] = y;
                bgl[(size_t)gi * 3 + 2] = z;
            }
        }
    }
}

// Pass 2: sep0 partial = sum over this block's non-bg pixels of 300/(1+||p-mean0||^2).
// grid = (P2_GX, B), 1024 threads; partial -> p2part[b*P2_GX + bx]  (no atomics)
__global__ void k_pass2(const float* __restrict__ pred, const float* __restrict__ targ,
                        const float* __restrict__ acc, float* __restrict__ p2part, int N) {
    __shared__ float s_w[16];
    int tid = threadIdx.x;
    int b = blockIdx.y;
    const float* g = acc + (size_t)b * ACC_STRIDE;
    float safe0 = fmaxf(g[OFF_CNT + 0], 1.0f);
    float m0x = g[OFF_SUM + 0] / safe0;
    float m0y = g[OFF_SUM + 1] / safe0;
    float m0z = g[OFF_SUM + 2] / safe0;

    const float* base_p = pred + (size_t)b * 3 * N;
    const float* base_t = targ + (size_t)b * 3 * N;
    const float4* p0 = (const float4*)(base_p);
    const float4* p1 = (const float4*)(base_p + N);
    const float4* p2 = (const float4*)(base_p + 2 * N);
    const float4* t0 = (const float4*)(base_t);

    float local = 0.0f;
    int M = N >> 2;
    for (int i = blockIdx.x * blockDim.x + tid; i < M; i += gridDim.x * blockDim.x) {
        float4 t = t0[i], a = p0[i], c = p1[i], d = p2[i];
        float ts[4] = {t.x, t.y, t.z, t.w};
        float xs[4] = {a.x, a.y, a.z, a.w};
        float ys[4] = {c.x, c.y, c.z, c.w};
        float zs[4] = {d.x, d.y, d.z, d.w};
#pragma unroll
        for (int j = 0; j < 4; j++) {
            float dx = xs[j] - m0x, dy = ys[j] - m0y, dz = zs[j] - m0z;
            float D = dx * dx + dy * dy + dz * dz;
            float m = (ts[j] > 2.0f) ? LAMBDA_SEP : 0.0f;   // non-bg iff t>=4
            local = fmaf(m, __builtin_amdgcn_rcpf(1.0f + D), local);
        }
    }
    if (blockIdx.x == 0) {
        for (int i = (M << 2) + tid; i < N; i += blockDim.x) {
            float dx = base_p[i] - m0x, dy = base_p[N + i] - m0y, dz = base_p[2 * N + i] - m0z;
            float D = dx * dx + dy * dy + dz * dz;
            float m = (base_t[i] > 2.0f) ? LAMBDA_SEP : 0.0f;
            local = fmaf(m, __builtin_amdgcn_rcpf(1.0f + D), local);
        }
    }
#pragma unroll
    for (int o = 32; o > 0; o >>= 1) local += __shfl_down(local, o, 64);
    int wv = tid >> 6;
    if ((tid & 63) == 0) s_w[wv] = local;
    __syncthreads();
    if (tid == 0) {
        float s = 0.0f;
        int nw = blockDim.x >> 6;
        for (int i = 0; i < nw; i++) s += s_w[i];
        p2part[(size_t)b * P2_GX + blockIdx.x] = s;
    }
}

// Pass 3: one k per lane. Tiles of bg pixels staged in LDS; each wave walks 64
// pixels with LDS-broadcast reads; lane accumulates for its own mean k.
// grid = (P3_GX, B); partials -> p3part[(b*P3_GX + bx)*64 + k]
__global__ void k_pass3(const float* __restrict__ bglist, const unsigned* __restrict__ bgcnt,
                        const float* __restrict__ acc, float* __restrict__ p3part, int maxbg) {
    __shared__ float s_px[P3_TILE * 3];
    __shared__ float s_part[4][NINST];
    int tid = threadIdx.x;
    int lane = tid & 63;
    int wv = tid >> 6;
    int b = blockIdx.y;
    const float* g = acc + (size_t)b * ACC_STRIDE;
    // lane's own mean (k = lane); lane 0 computes k=0, result ignored by k_final
    float safe = fmaxf(g[OFF_CNT + lane], 1.0f);
    float mx = g[OFF_SUM + lane * 3 + 0] / safe;
    float my = g[OFF_SUM + lane * 3 + 1] / safe;
    float mz = g[OFF_SUM + lane * 3 + 2] / safe;

    int nb = min((int)bgcnt[(size_t)b * CNT_STRIDE], maxbg);
    const float* bgl = bglist + (size_t)b * maxbg * 3;

    float lacc = 0.0f;
    int ntiles = (nb + P3_TILE - 1) / P3_TILE;
    for (int tile = blockIdx.x; tile < ntiles; tile += gridDim.x) {
        int base = tile * P3_TILE;
        int cnt = min(P3_TILE, nb - base);           // pixels in this tile
        __syncthreads();
        for (int i = tid; i < cnt * 3; i += blockDim.x) s_px[i] = bgl[(size_t)base * 3 + i];
        __syncthreads();
        // wave wv handles pixels [wv*64, wv*64+64) of the tile
        int lim = cnt - wv * 64;
        lim = lim < 0 ? 0 : (lim > 64 ? 64 : lim);
        const float* px = &s_px[wv * 64 * 3];
        for (int j = 0; j < lim; j++) {
            float x = px[j * 3 + 0];                 // broadcast: all lanes same addr
            float y = px[j * 3 + 1];
            float z = px[j * 3 + 2];
            float dx = x - mx, dy = y - my, dz = z - mz;
            float D = dx * dx + dy * dy + dz * dz;
            lacc += LAMBDA_SEP * __builtin_amdgcn_rcpf(1.0f + D);
        }
    }
    s_part[wv][lane] = lacc;
    __syncthreads();
    if (tid < NINST) {
        p3part[((size_t)b * P3_GX + blockIdx.x) * NINST + tid] =
            s_part[0][tid] + s_part[1][tid] + s_part[2][tid] + s_part[3][tid];
    }
}

// Pass 4: final per-image loss + batch mean. 1 block, 64 threads.
__global__ void k_final(const float* __restrict__ acc, const float* __restrict__ p2part,
                        const float* __restrict__ p3part, const unsigned char* __restrict__ nobg,
                        float* __restrict__ out, int N, int B) {
    int tid = threadIdx.x;  // 0..63
    float total = 0.0f;
    for (int b = 0; b < B; b++) {
        const float* g = acc + (size_t)b * ACC_STRIDE;
        float c = g[OFF_CNT + tid];
        float c0 = g[OFF_CNT + 0];
        bool incl = (c > 0.0f);
        if (tid == 0 && nobg[b] != 0) incl = false;
        float safe = fmaxf(c, 1.0f);
        float var = (tid == 0 ? g[OFF_H0] : g[OFF_H255 + tid]) / (3.0f * safe);
        float sepnum;
        if (tid == 0) {
            float s = 0.0f;
            for (int i = 0; i < P2_GX; i++) s += p2part[(size_t)b * P2_GX + i];
            sepnum = s;
        } else {
            float s = 0.0f;
#pragma unroll
            for (int j = 0; j < P3_GX; j++) s += p3part[((size_t)b * P3_GX + j) * NINST + tid];
            sepnum = s;
        }
        float denom = (tid == 0) ? fmaxf((float)N - c0, 1.0f) : fmaxf(c0, 1.0f);
        float sep = sepnum / denom;
        float w = 10.0f / sqrtf(safe);
        float term = incl ? (var + w * sep) : 0.0f;
        float cnt = incl ? 1.0f : 0.0f;
#pragma unroll
        for (int o = 32; o > 0; o >>= 1) {
            term += __shfl_down(term, o, 64);
            cnt += __shfl_down(cnt, o, 64);
        }
        if (tid == 0) total += term / fmaxf(cnt, 1.0f);
    }
    if (tid == 0) out[0] = total / (float)B;
}

extern "C" void kernel_launch(void* const* d_in, const int* in_sizes, int n_in,
                              void* d_out, int out_size, void* d_ws, size_t ws_size,
                              hipStream_t stream) {
    const float* pred = (const float*)d_in[0];
    const float* targ = (const float*)d_in[1];
    const unsigned char* nobg = (const unsigned char*)d_in[2];
    float* out = (float*)d_out;

    int B = in_sizes[2];            // no_bg has B elements
    int N = in_sizes[0] / (3 * B);  // pixels per image

    // ws layout
    float* acc = (float*)d_ws;
    size_t acc_bytes = (size_t)B * ACC_STRIDE * sizeof(float);
    unsigned* bgcnt = (unsigned*)((char*)d_ws + acc_bytes);          // B counters, stride CNT_STRIDE
    size_t head = acc_bytes + 4096;                                  // zeroed region
    float* p2part = (float*)((char*)d_ws + head);
    size_t p2_bytes = (size_t)B * P2_GX * sizeof(float);
    float* p3part = p2part + (size_t)B * P2_GX;
    size_t p3_bytes = (size_t)B * P3_GX * NINST * sizeof(float);
    size_t list_off = head + p2_bytes + p3_bytes;
    list_off = (list_off + 255) & ~(size_t)255;
    float* bglist = (float*)((char*)d_ws + list_off);

    int maxbg = 0;
    if (ws_size > list_off) {
        size_t cap = (ws_size - list_off) / ((size_t)B * 3 * sizeof(float));
        maxbg = (int)(cap < (size_t)131072 ? cap : (size_t)131072);
    }

    hipMemsetAsync(d_ws, 0, head, stream);  // zero accumulators + bg counters

    dim3 g1(P1_GX, B);
    k_pass1<<<g1, dim3(P1_THREADS), 0, stream>>>(pred, targ, acc, bgcnt, bglist, maxbg, N);
    dim3 g2(P2_GX, B);
    k_pass2<<<g2, dim3(1024), 0, stream>>>(pred, targ, acc, p2part, N);
    dim3 g3(P3_GX, B);
    k_pass3<<<g3, dim3(256), 0, stream>>>(bglist, bgcnt, acc, p3part, maxbg);
    k_final<<<dim3(1), dim3(64), 0, stream>>>(acc, p2part, p3part, nobg, out, N, B);
}